// Round 1
// baseline (148.982 us; speedup 1.0000x reference)
//
#include <hip/hip_runtime.h>

#define IN_F 256
#define HID 512
#define OUT_F 2048
#define N_HEADS 8
#define BATCH 4096

typedef __bf16 bf16_t;
typedef bf16_t bf16x8 __attribute__((ext_vector_type(8)));
typedef float f32x4 __attribute__((ext_vector_type(4)));

__device__ inline unsigned short f2bf(float f) {
  union { float f; unsigned u; } v; v.f = f;
  unsigned u = v.u;
  unsigned r = (u + 0x7FFFu + ((u >> 16) & 1u)) >> 16;  // RNE
  return (unsigned short)r;
}

// ---------------- bucket rows by head (single block) ----------------
__global__ __launch_bounds__(1024) void bucket_kernel(const int* __restrict__ idx,
                                                      int* __restrict__ order,
                                                      int* __restrict__ offsets) {
  __shared__ int cnt[N_HEADS];
  __shared__ int base[N_HEADS + 1];
  __shared__ int cur[N_HEADS];
  int tid = threadIdx.x;
  if (tid < N_HEADS) cnt[tid] = 0;
  __syncthreads();
  for (int i = tid; i < BATCH; i += 1024) atomicAdd(&cnt[idx[i]], 1);
  __syncthreads();
  if (tid == 0) {
    int acc = 0;
    for (int h = 0; h < N_HEADS; ++h) { base[h] = acc; cur[h] = acc; acc += cnt[h]; }
    base[N_HEADS] = acc;
  }
  __syncthreads();
  if (tid < N_HEADS + 1) offsets[tid] = base[tid];
  for (int i = tid; i < BATCH; i += 1024) {
    int pos = atomicAdd(&cur[idx[i]], 1);
    order[pos] = i;
  }
}

// ---------------- gather X rows into sorted order, fp32 -> bf16 ----------------
__global__ __launch_bounds__(256) void gather_x_kernel(const float* __restrict__ X,
                                                       const int* __restrict__ order,
                                                       unsigned short* __restrict__ Xg) {
  int p = blockIdx.x;
  int r = order[p];
  Xg[(size_t)p * IN_F + threadIdx.x] = f2bf(X[(size_t)r * IN_F + threadIdx.x]);
}

// ---------------- transpose + convert: W [H][K][N] fp32 -> Wt [H][N][K] bf16 ----------------
__global__ __launch_bounds__(256) void transpose_kernel(const float* __restrict__ W,
                                                        unsigned short* __restrict__ Wt,
                                                        int K, int N) {
  __shared__ float tile[32][33];
  int h = blockIdx.z;
  int n0 = blockIdx.x * 32;
  int k0 = blockIdx.y * 32;
  const float* Wh = W + (size_t)h * K * N;
  unsigned short* Wth = Wt + (size_t)h * K * N;
  int c = threadIdx.x & 31;
  int r = threadIdx.x >> 5;  // 0..7
  for (int rr = r; rr < 32; rr += 8)
    tile[rr][c] = Wh[(size_t)(k0 + rr) * N + n0 + c];
  __syncthreads();
  for (int rr = r; rr < 32; rr += 8)
    Wth[(size_t)(n0 + rr) * K + k0 + c] = f2bf(tile[c][rr]);
}

// ---------------- grouped GEMM, 64x64 tile, mfma 16x16x32 bf16 ----------------
// A: [BATCH][K] bf16 (sorted rows). Wt: [H][NTOT][K] bf16. bias: [H][NTOT] fp32.
// EPI==0: Hout[p][n] = bf16(relu(acc + bias))   (sorted order)
// EPI==1: Out[order[p]][n] = acc + bias          (fp32 scatter)
template <int K, int NTOT, int EPI>
__global__ __launch_bounds__(256) void gemm_kernel(const unsigned short* __restrict__ A,
                                                   const unsigned short* __restrict__ Wt,
                                                   const float* __restrict__ bias,
                                                   const int* __restrict__ offsets,
                                                   const int* __restrict__ order,
                                                   unsigned short* __restrict__ Hout,
                                                   float* __restrict__ Out) {
  constexpr int BM = 64, BN = 64, BK = 32;
  __shared__ __align__(16) unsigned short As[BM * BK];
  __shared__ __align__(16) unsigned short Bs[BN * BK];

  // map blockIdx.y -> (head, row tile)
  int my = blockIdx.y;
  int off[N_HEADS + 1];
#pragma unroll
  for (int i = 0; i <= N_HEADS; ++i) off[i] = offsets[i];
  int head = -1, row0 = 0, rows = 0, acc_t = 0;
#pragma unroll
  for (int h = 0; h < N_HEADS; ++h) {
    int cnt = off[h + 1] - off[h];
    int t = (cnt + BM - 1) / BM;
    if (head < 0 && my < acc_t + t) {
      head = h;
      int lt = my - acc_t;
      row0 = off[h] + lt * BM;
      rows = min(BM, cnt - lt * BM);
    }
    acc_t += t;
  }
  if (head < 0) return;

  int n0 = blockIdx.x * BN;
  const unsigned short* Bh = Wt + (size_t)head * NTOT * K;

  int tid = threadIdx.x;
  int wave = tid >> 6;
  int lane = tid & 63;
  int q = lane >> 4;
  int l16 = lane & 15;

  f32x4 acc[4];
#pragma unroll
  for (int i = 0; i < 4; ++i) acc[i] = (f32x4){0.f, 0.f, 0.f, 0.f};

  // staging: thread t loads 16B (8 bf16): row = t/4, elem offset = (t%4)*8
  int srow = tid >> 2;
  int scol = (tid & 3) * 8;

  for (int k0 = 0; k0 < K; k0 += BK) {
    uint4 av = make_uint4(0, 0, 0, 0);
    if (srow < rows)
      av = *(const uint4*)(A + (size_t)(row0 + srow) * K + k0 + scol);
    uint4 bv = *(const uint4*)(Bh + (size_t)(n0 + srow) * K + k0 + scol);
    __syncthreads();  // previous iteration's LDS reads complete
    *(uint4*)(As + srow * BK + scol) = av;
    *(uint4*)(Bs + srow * BK + scol) = bv;
    __syncthreads();

    bf16x8 af = *(const bf16x8*)(As + (wave * 16 + l16) * BK + q * 8);
#pragma unroll
    for (int nc = 0; nc < 4; ++nc) {
      bf16x8 bfr = *(const bf16x8*)(Bs + (nc * 16 + l16) * BK + q * 8);
      acc[nc] = __builtin_amdgcn_mfma_f32_16x16x32_bf16(af, bfr, acc[nc], 0, 0, 0);
    }
  }

#pragma unroll
  for (int nc = 0; nc < 4; ++nc) {
    int n = n0 + nc * 16 + l16;
    float bval = bias[(size_t)head * NTOT + n];
#pragma unroll
    for (int r = 0; r < 4; ++r) {
      int m = wave * 16 + q * 4 + r;
      if (m < rows) {
        int p = row0 + m;
        float v = acc[nc][r] + bval;
        if (EPI == 0) {
          v = v > 0.f ? v : 0.f;
          Hout[(size_t)p * NTOT + n] = f2bf(v);
        } else {
          int rg = order[p];
          Out[(size_t)rg * NTOT + n] = v;
        }
      }
    }
  }
}

extern "C" void kernel_launch(void* const* d_in, const int* in_sizes, int n_in,
                              void* d_out, int out_size, void* d_ws, size_t ws_size,
                              hipStream_t stream) {
  const float* X = (const float*)d_in[0];
  const int* idxh = (const int*)d_in[1];
  const float* W1 = (const float*)d_in[2];
  const float* b1 = (const float*)d_in[3];
  const float* W2 = (const float*)d_in[4];
  const float* b2 = (const float*)d_in[5];
  float* out = (float*)d_out;

  char* ws = (char*)d_ws;
  int* order = (int*)ws;                    ws += (size_t)BATCH * 4;
  int* offsets = (int*)ws;                  ws += 64;  // 9 ints, padded for alignment
  unsigned short* Xg = (unsigned short*)ws; ws += (size_t)BATCH * IN_F * 2;
  unsigned short* W1t = (unsigned short*)ws; ws += (size_t)N_HEADS * IN_F * HID * 2;
  unsigned short* W2t = (unsigned short*)ws; ws += (size_t)N_HEADS * HID * OUT_F * 2;
  unsigned short* Hb = (unsigned short*)ws;  ws += (size_t)BATCH * HID * 2;

  bucket_kernel<<<dim3(1), dim3(1024), 0, stream>>>(idxh, order, offsets);
  transpose_kernel<<<dim3(HID / 32, IN_F / 32, N_HEADS), dim3(256), 0, stream>>>(W1, W1t, IN_F, HID);
  transpose_kernel<<<dim3(OUT_F / 32, HID / 32, N_HEADS), dim3(256), 0, stream>>>(W2, W2t, HID, OUT_F);
  gather_x_kernel<<<dim3(BATCH), dim3(256), 0, stream>>>(X, order, Xg);

  constexpr int MT = BATCH / 64 + N_HEADS;  // worst-case row tiles across heads
  gemm_kernel<IN_F, HID, 0><<<dim3(HID / 64, MT), dim3(256), 0, stream>>>(
      Xg, W1t, b1, offsets, order, Hb, nullptr);
  gemm_kernel<HID, OUT_F, 1><<<dim3(OUT_F / 64, MT), dim3(256), 0, stream>>>(
      Hb, W2t, b2, offsets, order, nullptr, out);
}

// Round 2
// 141.974 us; speedup vs baseline: 1.0494x; 1.0494x over previous
//
#include <hip/hip_runtime.h>

#define IN_F 256
#define HID 512
#define OUT_F 2048
#define N_HEADS 8
#define BATCH 4096

typedef __bf16 bf16_t;
typedef bf16_t bf16x8 __attribute__((ext_vector_type(8)));
typedef float f32x4 __attribute__((ext_vector_type(4)));

typedef __attribute__((address_space(1))) const unsigned int gu32;
typedef __attribute__((address_space(3))) unsigned int lu32;

__device__ inline unsigned short f2bf(float f) {
  union { float f; unsigned u; } v; v.f = f;
  unsigned u = v.u;
  unsigned r = (u + 0x7FFFu + ((u >> 16) & 1u)) >> 16;  // RNE
  return (unsigned short)r;
}

// ---------------- bucket rows by head (single block) ----------------
__global__ __launch_bounds__(1024) void bucket_kernel(const int* __restrict__ idx,
                                                      int* __restrict__ order,
                                                      int* __restrict__ offsets) {
  __shared__ int cnt[N_HEADS];
  __shared__ int base[N_HEADS + 1];
  __shared__ int cur[N_HEADS];
  int tid = threadIdx.x;
  if (tid < N_HEADS) cnt[tid] = 0;
  __syncthreads();
  for (int i = tid; i < BATCH; i += 1024) atomicAdd(&cnt[idx[i]], 1);
  __syncthreads();
  if (tid == 0) {
    int acc = 0;
    for (int h = 0; h < N_HEADS; ++h) { base[h] = acc; cur[h] = acc; acc += cnt[h]; }
    base[N_HEADS] = acc;
  }
  __syncthreads();
  if (tid < N_HEADS + 1) offsets[tid] = base[tid];
  for (int i = tid; i < BATCH; i += 1024) {
    int pos = atomicAdd(&cur[idx[i]], 1);
    order[pos] = i;
  }
}

// ---------------- gather X rows into sorted order, fp32 -> bf16 ----------------
__global__ __launch_bounds__(256) void gather_x_kernel(const float* __restrict__ X,
                                                       const int* __restrict__ order,
                                                       unsigned short* __restrict__ Xg) {
  int p = blockIdx.x;
  int r = order[p];
  Xg[(size_t)p * IN_F + threadIdx.x] = f2bf(X[(size_t)r * IN_F + threadIdx.x]);
}

// ---------------- transpose + convert: W [H][K][N] fp32 -> Wt [H][N][K] bf16 ----------------
__global__ __launch_bounds__(256) void transpose_kernel(const float* __restrict__ W,
                                                        unsigned short* __restrict__ Wt,
                                                        int K, int N) {
  __shared__ float tile[32][33];
  int h = blockIdx.z;
  int n0 = blockIdx.x * 32;
  int k0 = blockIdx.y * 32;
  const float* Wh = W + (size_t)h * K * N;
  unsigned short* Wth = Wt + (size_t)h * K * N;
  int c = threadIdx.x & 31;
  int r = threadIdx.x >> 5;  // 0..7
  for (int rr = r; rr < 32; rr += 8)
    tile[rr][c] = Wh[(size_t)(k0 + rr) * N + n0 + c];
  __syncthreads();
  for (int rr = r; rr < 32; rr += 8)
    Wth[(size_t)(n0 + rr) * K + k0 + c] = f2bf(tile[c][rr]);
}

// ---------------- grouped GEMM, 128x128 tile, mfma 16x16x32 bf16, global_load_lds ----
// A: [BATCH][K] bf16 (sorted rows). Wt: [H][NTOT][K] bf16. bias: [H][NTOT] fp32.
// EPI==0: Hout[p][n] = bf16(relu(acc + bias))   (sorted order)
// EPI==1: Out[order[p]][n] = acc + bias          (fp32 scatter)
template <int K, int NTOT, int EPI>
__global__ __launch_bounds__(256) void gemm128_kernel(const unsigned short* __restrict__ A,
                                                      const unsigned short* __restrict__ Wt,
                                                      const float* __restrict__ bias,
                                                      const int* __restrict__ offsets,
                                                      const int* __restrict__ order,
                                                      unsigned short* __restrict__ Hout,
                                                      float* __restrict__ Out) {
  constexpr int BM = 128, BN = 128, BK = 32;
  __shared__ __align__(16) unsigned short As[BM * BK];  // chunk c = rows [c*16, c*16+16), row-major [r][32]
  __shared__ __align__(16) unsigned short Bs[BN * BK];

  // map blockIdx.y -> (head, row tile)
  int my = blockIdx.y;
  int head = -1, row0 = 0, rows = 0, acc_t = 0;
#pragma unroll
  for (int h = 0; h < N_HEADS; ++h) {
    int o0 = offsets[h], o1 = offsets[h + 1];
    int cnt = o1 - o0;
    int t = (cnt + BM - 1) / BM;
    if (head < 0 && my < acc_t + t) {
      head = h;
      int lt = my - acc_t;
      row0 = o0 + lt * BM;
      rows = min(BM, cnt - lt * BM);
    }
    acc_t += t;
  }
  if (head < 0) return;

  int n0 = blockIdx.x * BN;
  const unsigned short* Bh = Wt + (size_t)head * (size_t)NTOT * K;

  int tid = threadIdx.x;
  int wave = tid >> 6;
  int lane = tid & 63;
  int q = lane >> 4;    // quad 0..3 -> k = q*8 + j
  int l16 = lane & 15;

  // staging: chunk c (16 rows x 32 cols = 1024 B); lane l covers row l>>2, cols (l&3)*8..+8
  // LDS dest = chunk base + lane*16 (hardware adds lane*size)
  int ldrow = lane >> 2;        // 0..15
  int ldcol = (lane & 3) * 8;   // element offset
  int c0 = wave * 2, c1 = wave * 2 + 1;
  // clamp A rows into valid range (dup rows discarded in epilogue; avoids OOB)
  int ar0 = row0 + min(c0 * 16 + ldrow, rows - 1);
  int ar1 = row0 + min(c1 * 16 + ldrow, rows - 1);
  const unsigned short* aptr0 = A + (size_t)ar0 * K + ldcol;
  const unsigned short* aptr1 = A + (size_t)ar1 * K + ldcol;
  const unsigned short* bptr0 = Bh + (size_t)(n0 + c0 * 16 + ldrow) * K + ldcol;
  const unsigned short* bptr1 = Bh + (size_t)(n0 + c1 * 16 + ldrow) * K + ldcol;
  unsigned short* lA0 = As + c0 * 512;  // wave-uniform LDS base
  unsigned short* lA1 = As + c1 * 512;
  unsigned short* lB0 = Bs + c0 * 512;
  unsigned short* lB1 = Bs + c1 * 512;

  int w_m = wave >> 1, w_n = wave & 1;  // 2x2 wave grid, each wave 64x64

  f32x4 acc[4][4];
#pragma unroll
  for (int i = 0; i < 4; ++i)
#pragma unroll
    for (int j = 0; j < 4; ++j) acc[i][j] = (f32x4){0.f, 0.f, 0.f, 0.f};

  for (int k0 = 0; k0 < K; k0 += BK) {
    __builtin_amdgcn_global_load_lds((gu32*)aptr0, (lu32*)lA0, 16, 0, 0);
    __builtin_amdgcn_global_load_lds((gu32*)aptr1, (lu32*)lA1, 16, 0, 0);
    __builtin_amdgcn_global_load_lds((gu32*)bptr0, (lu32*)lB0, 16, 0, 0);
    __builtin_amdgcn_global_load_lds((gu32*)bptr1, (lu32*)lB1, 16, 0, 0);
    aptr0 += BK; aptr1 += BK; bptr0 += BK; bptr1 += BK;
    __syncthreads();  // drains vmcnt before barrier (compiler-emitted)

    bf16x8 af[4], bfr[4];
#pragma unroll
    for (int i = 0; i < 4; ++i) {
      af[i] = *(const bf16x8*)(As + (w_m * 64 + i * 16 + l16) * BK + q * 8);
      bfr[i] = *(const bf16x8*)(Bs + (w_n * 64 + i * 16 + l16) * BK + q * 8);
    }
#pragma unroll
    for (int mi = 0; mi < 4; ++mi)
#pragma unroll
      for (int ni = 0; ni < 4; ++ni)
        acc[mi][ni] = __builtin_amdgcn_mfma_f32_16x16x32_bf16(af[mi], bfr[ni], acc[mi][ni], 0, 0, 0);
    __syncthreads();  // all waves done reading before next overwrite
  }

  // epilogue: C/D layout col=l16, row=q*4+r per 16x16 frag
  float bval[4];
#pragma unroll
  for (int ni = 0; ni < 4; ++ni)
    bval[ni] = bias[(size_t)head * NTOT + n0 + w_n * 64 + ni * 16 + l16];

#pragma unroll
  for (int mi = 0; mi < 4; ++mi) {
#pragma unroll
    for (int r = 0; r < 4; ++r) {
      int m = w_m * 64 + mi * 16 + q * 4 + r;
      if (m < rows) {
        int p = row0 + m;
        if (EPI == 0) {
#pragma unroll
          for (int ni = 0; ni < 4; ++ni) {
            int n = n0 + w_n * 64 + ni * 16 + l16;
            float v = acc[mi][ni][r] + bval[ni];
            v = v > 0.f ? v : 0.f;
            Hout[(size_t)p * NTOT + n] = f2bf(v);
          }
        } else {
          int rg = order[p];
#pragma unroll
          for (int ni = 0; ni < 4; ++ni) {
            int n = n0 + w_n * 64 + ni * 16 + l16;
            Out[(size_t)rg * NTOT + n] = acc[mi][ni][r] + bval[ni];
          }
        }
      }
    }
  }
}

extern "C" void kernel_launch(void* const* d_in, const int* in_sizes, int n_in,
                              void* d_out, int out_size, void* d_ws, size_t ws_size,
                              hipStream_t stream) {
  const float* X = (const float*)d_in[0];
  const int* idxh = (const int*)d_in[1];
  const float* W1 = (const float*)d_in[2];
  const float* b1 = (const float*)d_in[3];
  const float* W2 = (const float*)d_in[4];
  const float* b2 = (const float*)d_in[5];
  float* out = (float*)d_out;

  char* ws = (char*)d_ws;
  int* order = (int*)ws;                     ws += (size_t)BATCH * 4;
  int* offsets = (int*)ws;                   ws += 64;
  unsigned short* Xg = (unsigned short*)ws;  ws += (size_t)BATCH * IN_F * 2;
  unsigned short* W1t = (unsigned short*)ws; ws += (size_t)N_HEADS * IN_F * HID * 2;
  unsigned short* W2t = (unsigned short*)ws; ws += (size_t)N_HEADS * HID * OUT_F * 2;
  unsigned short* Hb = (unsigned short*)ws;  ws += (size_t)BATCH * HID * 2;

  bucket_kernel<<<dim3(1), dim3(1024), 0, stream>>>(idxh, order, offsets);
  transpose_kernel<<<dim3(HID / 32, IN_F / 32, N_HEADS), dim3(256), 0, stream>>>(W1, W1t, IN_F, HID);
  transpose_kernel<<<dim3(OUT_F / 32, HID / 32, N_HEADS), dim3(256), 0, stream>>>(W2, W2t, HID, OUT_F);
  gather_x_kernel<<<dim3(BATCH), dim3(256), 0, stream>>>(X, order, Xg);

  constexpr int MT = BATCH / 128 + N_HEADS;  // worst-case row tiles across heads
  gemm128_kernel<IN_F, HID, 0><<<dim3(HID / 128, MT), dim3(256), 0, stream>>>(
      Xg, W1t, b1, offsets, order, Hb, nullptr);
  gemm128_kernel<HID, OUT_F, 1><<<dim3(OUT_F / 128, MT), dim3(256), 0, stream>>>(
      Hb, W2t, b2, offsets, order, nullptr, out);
}

// Round 3
// 131.980 us; speedup vs baseline: 1.1288x; 1.0757x over previous
//
#include <hip/hip_runtime.h>

#define IN_F 256
#define HID 512
#define OUT_F 2048
#define N_HEADS 8
#define BATCH 4096

typedef __bf16 bf16_t;
typedef bf16_t bf16x8 __attribute__((ext_vector_type(8)));
typedef float f32x4 __attribute__((ext_vector_type(4)));

typedef __attribute__((address_space(1))) const unsigned int gu32;
typedef __attribute__((address_space(3))) unsigned int lu32;

__device__ inline unsigned short f2bf(float f) {
  union { float f; unsigned u; } v; v.f = f;
  unsigned u = v.u;
  unsigned r = (u + 0x7FFFu + ((u >> 16) & 1u)) >> 16;  // RNE
  return (unsigned short)r;
}

// ---------------- bucket rows by head (single block) ----------------
__global__ __launch_bounds__(1024) void bucket_kernel(const int* __restrict__ idx,
                                                      int* __restrict__ order,
                                                      int* __restrict__ offsets) {
  __shared__ int cnt[N_HEADS];
  __shared__ int base[N_HEADS + 1];
  __shared__ int cur[N_HEADS];
  int tid = threadIdx.x;
  if (tid < N_HEADS) cnt[tid] = 0;
  __syncthreads();
  for (int i = tid; i < BATCH; i += 1024) atomicAdd(&cnt[idx[i]], 1);
  __syncthreads();
  if (tid == 0) {
    int acc = 0;
    for (int h = 0; h < N_HEADS; ++h) { base[h] = acc; cur[h] = acc; acc += cnt[h]; }
    base[N_HEADS] = acc;
  }
  __syncthreads();
  if (tid < N_HEADS + 1) offsets[tid] = base[tid];
  for (int i = tid; i < BATCH; i += 1024) {
    int pos = atomicAdd(&cur[idx[i]], 1);
    order[pos] = i;
  }
}

// ---------------- fused prep: gather X (fp32->bf16, sorted) + transpose W1,W2 ----
// grid layout: [0,512)        gather, 8 rows/block
//              [512,768)      W1 transpose 64x64 tiles (8 n x 4 k x 8 h)
//              [768,2816)     W2 transpose 64x64 tiles (32 n x 8 k x 8 h)
__device__ inline void transpose64(const float* __restrict__ W,
                                   unsigned short* __restrict__ Wt,
                                   int K, int N, int b, int nt, int kt,
                                   float (*tile)[65]) {
  int per_head = nt * kt;
  int h = b / per_head;
  int rem = b % per_head;
  int n0 = (rem % nt) * 64;
  int k0 = (rem / nt) * 64;
  const float* Wh = W + (size_t)h * K * N;
  unsigned short* Wth = Wt + (size_t)h * K * N;
  int c = threadIdx.x & 63;
  int r0 = threadIdx.x >> 6;  // 0..3
  for (int rr = r0; rr < 64; rr += 4)
    tile[rr][c] = Wh[(size_t)(k0 + rr) * N + n0 + c];
  __syncthreads();
  for (int rr = r0; rr < 64; rr += 4)
    Wth[(size_t)(n0 + rr) * K + k0 + c] = f2bf(tile[c][rr]);
}

__global__ __launch_bounds__(256) void prep_kernel(const float* __restrict__ X,
                                                   const int* __restrict__ order,
                                                   unsigned short* __restrict__ Xg,
                                                   const float* __restrict__ W1,
                                                   unsigned short* __restrict__ W1t,
                                                   const float* __restrict__ W2,
                                                   unsigned short* __restrict__ W2t) {
  __shared__ float tile[64][65];
  int b = blockIdx.x;
  if (b < 512) {
    // gather: 8 rows per block, 4 rows per pass, 64 float4-lanes per row
    int c4 = threadIdx.x & 63;
    int rloc = threadIdx.x >> 6;  // 0..3
#pragma unroll
    for (int pass = 0; pass < 2; ++pass) {
      int p = b * 8 + pass * 4 + rloc;
      int src = order[p];
      float4 v = ((const float4*)(X + (size_t)src * IN_F))[c4];
      ushort4 o;
      o.x = f2bf(v.x); o.y = f2bf(v.y); o.z = f2bf(v.z); o.w = f2bf(v.w);
      ((ushort4*)(Xg + (size_t)p * IN_F))[c4] = o;
    }
  } else if (b < 768) {
    transpose64(W1, W1t, IN_F, HID, b - 512, HID / 64, IN_F / 64, tile);
  } else {
    transpose64(W2, W2t, HID, OUT_F, b - 768, OUT_F / 64, HID / 64, tile);
  }
}

// ---------------- grouped GEMM, 128x128 tile, mfma 16x16x32 bf16, global_load_lds ----
// A: [BATCH][K] bf16 (sorted rows). Wt: [H][NTOT][K] bf16. bias: [H][NTOT] fp32.
// EPI==0: Hout[p][n] = bf16(relu(acc + bias))   (sorted order)
// EPI==1: Out[order[p]][n] = acc + bias          (fp32 scatter)
template <int K, int NTOT, int EPI>
__global__ __launch_bounds__(256) void gemm128_kernel(const unsigned short* __restrict__ A,
                                                      const unsigned short* __restrict__ Wt,
                                                      const float* __restrict__ bias,
                                                      const int* __restrict__ offsets,
                                                      const int* __restrict__ order,
                                                      unsigned short* __restrict__ Hout,
                                                      float* __restrict__ Out) {
  constexpr int BM = 128, BN = 128, BK = 32;
  __shared__ __align__(16) unsigned short As[BM * BK];
  __shared__ __align__(16) unsigned short Bs[BN * BK];

  int my = blockIdx.y;
  int head = -1, row0 = 0, rows = 0, acc_t = 0;
#pragma unroll
  for (int h = 0; h < N_HEADS; ++h) {
    int o0 = offsets[h], o1 = offsets[h + 1];
    int cnt = o1 - o0;
    int t = (cnt + BM - 1) / BM;
    if (head < 0 && my < acc_t + t) {
      head = h;
      int lt = my - acc_t;
      row0 = o0 + lt * BM;
      rows = min(BM, cnt - lt * BM);
    }
    acc_t += t;
  }
  if (head < 0) return;

  int n0 = blockIdx.x * BN;
  const unsigned short* Bh = Wt + (size_t)head * (size_t)NTOT * K;

  int tid = threadIdx.x;
  int wave = tid >> 6;
  int lane = tid & 63;
  int q = lane >> 4;
  int l16 = lane & 15;

  int ldrow = lane >> 2;
  int ldcol = (lane & 3) * 8;
  int c0 = wave * 2, c1 = wave * 2 + 1;
  int ar0 = row0 + min(c0 * 16 + ldrow, rows - 1);
  int ar1 = row0 + min(c1 * 16 + ldrow, rows - 1);
  const unsigned short* aptr0 = A + (size_t)ar0 * K + ldcol;
  const unsigned short* aptr1 = A + (size_t)ar1 * K + ldcol;
  const unsigned short* bptr0 = Bh + (size_t)(n0 + c0 * 16 + ldrow) * K + ldcol;
  const unsigned short* bptr1 = Bh + (size_t)(n0 + c1 * 16 + ldrow) * K + ldcol;
  unsigned short* lA0 = As + c0 * 512;
  unsigned short* lA1 = As + c1 * 512;
  unsigned short* lB0 = Bs + c0 * 512;
  unsigned short* lB1 = Bs + c1 * 512;

  int w_m = wave >> 1, w_n = wave & 1;

  f32x4 acc[4][4];
#pragma unroll
  for (int i = 0; i < 4; ++i)
#pragma unroll
    for (int j = 0; j < 4; ++j) acc[i][j] = (f32x4){0.f, 0.f, 0.f, 0.f};

  for (int k0 = 0; k0 < K; k0 += BK) {
    __builtin_amdgcn_global_load_lds((gu32*)aptr0, (lu32*)lA0, 16, 0, 0);
    __builtin_amdgcn_global_load_lds((gu32*)aptr1, (lu32*)lA1, 16, 0, 0);
    __builtin_amdgcn_global_load_lds((gu32*)bptr0, (lu32*)lB0, 16, 0, 0);
    __builtin_amdgcn_global_load_lds((gu32*)bptr1, (lu32*)lB1, 16, 0, 0);
    aptr0 += BK; aptr1 += BK; bptr0 += BK; bptr1 += BK;
    __syncthreads();

    bf16x8 af[4], bfr[4];
#pragma unroll
    for (int i = 0; i < 4; ++i) {
      af[i] = *(const bf16x8*)(As + (w_m * 64 + i * 16 + l16) * BK + q * 8);
      bfr[i] = *(const bf16x8*)(Bs + (w_n * 64 + i * 16 + l16) * BK + q * 8);
    }
#pragma unroll
    for (int mi = 0; mi < 4; ++mi)
#pragma unroll
      for (int ni = 0; ni < 4; ++ni)
        acc[mi][ni] = __builtin_amdgcn_mfma_f32_16x16x32_bf16(af[mi], bfr[ni], acc[mi][ni], 0, 0, 0);
    __syncthreads();
  }

  float bval[4];
#pragma unroll
  for (int ni = 0; ni < 4; ++ni)
    bval[ni] = bias[(size_t)head * NTOT + n0 + w_n * 64 + ni * 16 + l16];

#pragma unroll
  for (int mi = 0; mi < 4; ++mi) {
#pragma unroll
    for (int r = 0; r < 4; ++r) {
      int m = w_m * 64 + mi * 16 + q * 4 + r;
      if (m < rows) {
        int p = row0 + m;
        if (EPI == 0) {
#pragma unroll
          for (int ni = 0; ni < 4; ++ni) {
            int n = n0 + w_n * 64 + ni * 16 + l16;
            float v = acc[mi][ni][r] + bval[ni];
            v = v > 0.f ? v : 0.f;
            Hout[(size_t)p * NTOT + n] = f2bf(v);
          }
        } else {
          int rg = order[p];
#pragma unroll
          for (int ni = 0; ni < 4; ++ni) {
            int n = n0 + w_n * 64 + ni * 16 + l16;
            Out[(size_t)rg * NTOT + n] = acc[mi][ni][r] + bval[ni];
          }
        }
      }
    }
  }
}

extern "C" void kernel_launch(void* const* d_in, const int* in_sizes, int n_in,
                              void* d_out, int out_size, void* d_ws, size_t ws_size,
                              hipStream_t stream) {
  const float* X = (const float*)d_in[0];
  const int* idxh = (const int*)d_in[1];
  const float* W1 = (const float*)d_in[2];
  const float* b1 = (const float*)d_in[3];
  const float* W2 = (const float*)d_in[4];
  const float* b2 = (const float*)d_in[5];
  float* out = (float*)d_out;

  char* ws = (char*)d_ws;
  int* order = (int*)ws;                     ws += (size_t)BATCH * 4;
  int* offsets = (int*)ws;                   ws += 64;
  unsigned short* Xg = (unsigned short*)ws;  ws += (size_t)BATCH * IN_F * 2;
  unsigned short* W1t = (unsigned short*)ws; ws += (size_t)N_HEADS * IN_F * HID * 2;
  unsigned short* W2t = (unsigned short*)ws; ws += (size_t)N_HEADS * HID * OUT_F * 2;
  unsigned short* Hb = (unsigned short*)ws;  ws += (size_t)BATCH * HID * 2;

  bucket_kernel<<<dim3(1), dim3(1024), 0, stream>>>(idxh, order, offsets);
  prep_kernel<<<dim3(2816), dim3(256), 0, stream>>>(X, order, Xg, W1, W1t, W2, W2t);

  constexpr int MT = BATCH / 128 + N_HEADS;
  gemm128_kernel<IN_F, HID, 0><<<dim3(HID / 128, MT), dim3(256), 0, stream>>>(
      Xg, W1t, b1, offsets, order, Hb, nullptr);
  gemm128_kernel<HID, OUT_F, 1><<<dim3(OUT_F / 128, MT), dim3(256), 0, stream>>>(
      Hb, W2t, b2, offsets, order, nullptr, out);
}